// Round 6
// baseline (440.065 us; speedup 1.0000x reference)
//
#include <hip/hip_runtime.h>
#include <hip/hip_bf16.h>

using bf16 = __hip_bfloat16;
typedef short  short8  __attribute__((ext_vector_type(8)));
typedef float  float4_ __attribute__((ext_vector_type(4)));
typedef int    int4_   __attribute__((ext_vector_type(4)));

typedef __attribute__((address_space(1))) const void* gas_ptr;
typedef __attribute__((address_space(3))) void*       las_ptr;

#define MFMA_BF16(a, b, c) __builtin_amdgcn_mfma_f32_16x16x32_bf16((a), (b), (c), 0, 0, 0)

__device__ __forceinline__ float bf2f(bf16 v) { return __bfloat162float(v); }
__device__ __forceinline__ bf16  f2bf(float v) { return __float2bfloat16(v); }

#define BAR() do { asm volatile("" ::: "memory"); __builtin_amdgcn_s_barrier(); asm volatile("" ::: "memory"); } while (0)
#define WAITLGKM0() asm volatile("s_waitcnt lgkmcnt(0)" ::: "memory")

// ---------------------------------------------------------------------------
// fp32 -> bf16 conversion of X + 4 weights into workspace (verified r2 form).
// ---------------------------------------------------------------------------
__global__ __launch_bounds__(256)
void cvt_all(const float* __restrict__ X,  const float* __restrict__ Wq,
             const float* __restrict__ Wk, const float* __restrict__ Wv,
             const float* __restrict__ Wo,
             bf16* __restrict__ Xb,  bf16* __restrict__ Wqb,
             bf16* __restrict__ Wkb, bf16* __restrict__ Wvb,
             bf16* __restrict__ Wob)
{
    const size_t i = ((size_t)blockIdx.x * 256 + threadIdx.x) * 8;
    const float* src; bf16* dst; size_t off;
    if (i < 8388608)       { src = X;  dst = Xb;  off = i; }
    else if (i < 12582912) { src = Wq; dst = Wqb; off = i - 8388608; }
    else if (i < 16777216) { src = Wk; dst = Wkb; off = i - 12582912; }
    else if (i < 20971520) { src = Wv; dst = Wvb; off = i - 16777216; }
    else                   { src = Wo; dst = Wob; off = i - 20971520; }
    const float4_ a = *(const float4_*)(src + off);
    const float4_ b = *(const float4_*)(src + off + 4);
    union { short8 s; bf16 h[8]; } u;
#pragma unroll
    for (int j = 0; j < 4; ++j) { u.h[j] = f2bf(a[j]); u.h[j + 4] = f2bf(b[j]); }
    *(short8*)(dst + off) = u.s;
}

// ---------------------------------------------------------------------------
// 256x128 2-phase-per-tile MFMA GEMM (verified r4/r5: QKV 768 blocks = 3
// rounds, O-proj 256 = 1 round; T2 swizzle, counted vmcnt(5), tail drain,
// setprio). FROZEN this round.
// mode 0: scatter bf16 to Oq = q/k/v [3][B][NH][S][HD], N=6144 merged QKV.
// mode 1: row-major fp32 OF, N=2048.
// ---------------------------------------------------------------------------
__global__ __launch_bounds__(512, 2)
void gemm_bn128(const bf16* __restrict__ Ap, const bf16* __restrict__ Wp,
                bf16* __restrict__ Oq, float* __restrict__ OF, int mode)
{
    constexpr int NT = 32;                       // K=2048 / BK=64
    __shared__ bf16 As0[2 * 256 * 64];           // 64 KiB [buf][row][64]
    __shared__ bf16 Bs0[2 * 128 * 64];           // 32 KiB

    const int nwg  = gridDim.x * gridDim.y;
    const int bid0 = blockIdx.y * gridDim.x + blockIdx.x;
    const int cpx  = nwg >> 3;
    const int swzb = (bid0 & 7) * cpx + (bid0 >> 3);
    const int bn = (swzb % gridDim.x) * 128;
    const int bm = (swzb / gridDim.x) * 256;

    const int tid  = threadIdx.x;
    const int w    = tid >> 6;                   // 0..7
    const int ln   = tid & 63;
    const int r15  = ln & 15;
    const int quad = ln >> 4;
    const int wr   = w >> 1;                     // 0..3 (M)
    const int wc   = w & 1;                      // 0..1 (N)

    const int srow = ln >> 3;                                // 0..7
    const int scol = ((ln & 7) ^ srow) * 8;                  // elements
    const int w8   = w * 8;
    const int cx   = (r15 & 7) * 8;                          // read-side XOR

#define STAGE_A(pb, ts) do {                                                \
    _Pragma("unroll")                                                       \
    for (int c = 0; c < 4; ++c) {                                           \
        const int rl = c * 64 + w8;                                         \
        __builtin_amdgcn_global_load_lds(                                   \
            (gas_ptr)(Ap + (size_t)(bm + rl + srow) * 2048 + (ts) * 64 + scol), \
            (las_ptr)(As0 + (pb) * 16384 + rl * 64), 16, 0, 0);             \
    } } while (0)

#define STAGE_B0(pb, ts) do {                                               \
    const int rl = w8;                                                      \
    __builtin_amdgcn_global_load_lds(                                       \
        (gas_ptr)(Wp + (size_t)(bn + rl + srow) * 2048 + (ts) * 64 + scol), \
        (las_ptr)(Bs0 + (pb) * 8192 + rl * 64), 16, 0, 0);                  \
    } while (0)

#define STAGE_B1(pb, ts) do {                                               \
    const int rl = 64 + w8;                                                 \
    __builtin_amdgcn_global_load_lds(                                       \
        (gas_ptr)(Wp + (size_t)(bn + rl + srow) * 2048 + (ts) * 64 + scol), \
        (las_ptr)(Bs0 + (pb) * 8192 + rl * 64), 16, 0, 0);                  \
    } while (0)

#define LDA() do {                                                          \
    _Pragma("unroll")                                                       \
    for (int mi = 0; mi < 4; ++mi) {                                        \
        const int row = wr * 64 + mi * 16 + r15;                            \
        a[mi][0] = *(const short8*)(As0 + p * 16384 + row * 64 + ((quad * 8) ^ cx));      \
        a[mi][1] = *(const short8*)(As0 + p * 16384 + row * 64 + ((32 + quad * 8) ^ cx)); \
    } } while (0)

#define LDB(qn) do {                                                        \
    _Pragma("unroll")                                                       \
    for (int j = 0; j < 2; ++j) {                                           \
        const int row = wc * 64 + ((qn) * 2 + j) * 16 + r15;                \
        b[j][0] = *(const short8*)(Bs0 + p * 8192 + row * 64 + ((quad * 8) ^ cx));      \
        b[j][1] = *(const short8*)(Bs0 + p * 8192 + row * 64 + ((32 + quad * 8) ^ cx)); \
    } } while (0)

#define MM(qn) do {                                                         \
    __builtin_amdgcn_s_setprio(1);                                          \
    _Pragma("unroll")                                                       \
    for (int mi = 0; mi < 4; ++mi)                                          \
        _Pragma("unroll")                                                   \
        for (int j = 0; j < 2; ++j)                                         \
            _Pragma("unroll")                                               \
            for (int kk = 0; kk < 2; ++kk)                                  \
                acc[mi][(qn) * 2 + j] =                                     \
                    MFMA_BF16(a[mi][kk], b[j][kk], acc[mi][(qn) * 2 + j]);  \
    __builtin_amdgcn_s_setprio(0); } while (0)

    float4_ acc[4][4];
    const float4_ fzero = {0.f, 0.f, 0.f, 0.f};
#pragma unroll
    for (int i = 0; i < 4; ++i)
#pragma unroll
        for (int j = 0; j < 4; ++j) acc[i][j] = fzero;

    short8 a[4][2], b[2][2];

    STAGE_A(0, 0); STAGE_B0(0, 0); STAGE_B1(0, 0);
    STAGE_A(1, 1); STAGE_B0(1, 1);
    asm volatile("s_waitcnt vmcnt(5)" ::: "memory");
    BAR();

    for (int t = 0; t < NT; ++t) {
        const int p = t & 1, pq = p ^ 1;
        LDA(); LDB(0);
        if (t + 1 < NT) STAGE_B1(pq, t + 1);
        asm volatile("s_waitcnt lgkmcnt(8)" ::: "memory");
        BAR(); WAITLGKM0();
        MM(0);
        BAR();
        LDB(1);
        if (t + 2 < NT) { STAGE_A(p, t + 2); STAGE_B0(p, t + 2); }
        BAR(); WAITLGKM0();
        MM(1);
        if (t >= NT - 2) { asm volatile("s_waitcnt vmcnt(0)" ::: "memory"); }
        else             { asm volatile("s_waitcnt vmcnt(5)" ::: "memory"); }
        BAR();
    }

#pragma unroll
    for (int mi = 0; mi < 4; ++mi) {
#pragma unroll
        for (int ni = 0; ni < 4; ++ni) {
#pragma unroll
            for (int r = 0; r < 4; ++r) {
                const int row = bm + wr * 64 + mi * 16 + quad * 4 + r;
                const int col = bn + wc * 64 + ni * 16 + r15;
                const float v = acc[mi][ni][r];
                if (mode == 0) {
                    const int z = col >> 11, c2 = col & 2047;
                    const int h = c2 >> 7, d = c2 & 127;
                    const int bb = row >> 11, s = row & 2047;
                    Oq[(size_t)z * 8388608 + (((size_t)bb * 16 + h) * 2048 + s) * 128 + d] = f2bf(v);
                } else {
                    OF[(size_t)row * 2048 + col] = v;
                }
            }
        }
    }
#undef STAGE_A
#undef STAGE_B0
#undef STAGE_B1
#undef LDA
#undef LDB
#undef MM
}

// ---------------------------------------------------------------------------
// RoPE on Q and K ([B][NH][S][HD] bf16); folds 1/sqrt(128) into Q.
// ---------------------------------------------------------------------------
__global__ __launch_bounds__(256)
void rope_scale(bf16* __restrict__ Q, bf16* __restrict__ Kb)
{
    const int idx = blockIdx.x * 256 + threadIdx.x;
    const int d  = idx & 63;
    const int s  = (idx >> 6) & 2047;
    const int bh = idx >> 17;
    const size_t base = ((size_t)bh * 2048 + s) * 128;

    const float inv_freq = expf(-(float)d * (9.210340371976184f / 64.f));
    const float ang = (float)s * inv_freq;
    const float c = cosf(ang), sn = sinf(ang);
    const float sc = 0.08838834764831845f;

    const float q1 = bf2f(Q[base + d]), q2 = bf2f(Q[base + d + 64]);
    Q[base + d]      = f2bf((q1 * c - q2 * sn) * sc);
    Q[base + d + 64] = f2bf((q2 * c + q1 * sn) * sc);

    const float k1 = bf2f(Kb[base + d]), k2 = bf2f(Kb[base + d + 64]);
    Kb[base + d]      = f2bf(k1 * c - k2 * sn);
    Kb[base + d + 64] = f2bf(k2 * c + k1 * sn);
}

// ---------------------------------------------------------------------------
// Causal MFMA flash attention, v4 (pair-balanced + wave-per-strip):
//  - 256 blocks: block (pr,bh) owns strips pr and 15-pr (pair = 34 tile-units
//    for every pr -> balanced grid, verified r5).
//  - NEW: waves 0-3 own the lo strip, waves 4-7 the hi strip, 32 Q-rows per
//    wave (2 row-fragments). Each K-fragment / V-fragment LDS read is shared
//    by both row-fragments: 36 ds_read_b128 feed 64 MFMA per step (vs 34:32
//    in r5) -> block LDS reads drop 9248 -> 4896 b128, removing the 3.2:1
//    LDS:MFMA serialization (r4/r5 counter signature: MfmaUtil 8.5%).
//    Per-SIMD work stays balanced: each SIMD hosts one lo + one hi wave =
//    (2p+2)+(32-2p) = 34 steps.
//  - staging / T14 async-split / diagonal mask / setprio verbatim from r5.
// Q,K,V: [B][NH][S][HD] bf16 (Q pre-scaled); O: [B][S][NH][HD] bf16.
// ---------------------------------------------------------------------------
__global__ __launch_bounds__(512)
void flash_attn(const bf16* __restrict__ Qg, const bf16* __restrict__ Kg,
                const bf16* __restrict__ Vg, bf16* __restrict__ Og)
{
    constexpr int S = 2048;
    const int pr = blockIdx.x;            // 0..7: strip pair (pr, 15-pr)
    const int bh = blockIdx.y;
    const int b = bh >> 4, h = bh & 15;
    const size_t base = (size_t)bh * S * 128;
    const bf16* Qp = Qg + base;
    const bf16* Kp = Kg + base;
    const bf16* Vp = Vg + base;

    const int tid  = threadIdx.x;
    const int wave = tid >> 6;            // 0..7
    const int ln   = tid & 63;
    const int r15  = ln & 15;
    const int quad = ln >> 4;
    const int sid  = wave & 3;            // sub-strip index within strip
    const int hi   = wave >> 2;           // 0 = lo strip, 1 = hi strip

    __shared__ bf16 Ks[64][136];          // K tile, 17.0 KB
    __shared__ bf16 Vt[128][72];          // V tile transposed, 18.0 KB
    __shared__ bf16 Ps[8][32][72];        // per-wave P (2 row-frags), 36.9 KB

    const int strip = hi ? (15 - pr) : pr;
    const int qrow0 = strip * 128 + sid * 32;   // this wave's 32 rows
    const int dt    = qrow0 >> 6;               // diagonal K-tile (rows 0..31
                                                // stay in one 64-tile: qrow0%64 in {0,32})
    const int ktmax = 2 * (15 - pr) + 1;        // staging range (hi strip)

    // Q fragments: 2 row-frags x 4 k-slices, straight global->reg
    short8 qf[2][4];
#pragma unroll
    for (int rf = 0; rf < 2; ++rf)
#pragma unroll
        for (int ks = 0; ks < 4; ++ks)
            qf[rf][ks] = *(const short8*)&Qp[(size_t)(qrow0 + rf * 16 + r15) * 128
                                             + ks * 32 + quad * 8];

    float4_ acc_o[2][8];
    const float4_ fzero = {0.f, 0.f, 0.f, 0.f};
#pragma unroll
    for (int rf = 0; rf < 2; ++rf)
#pragma unroll
        for (int of = 0; of < 8; ++of) acc_o[rf][of] = fzero;
    float m_run[2][4], l_run[2][4];
#pragma unroll
    for (int rf = 0; rf < 2; ++rf)
#pragma unroll
        for (int r = 0; r < 4; ++r) { m_run[rf][r] = -__builtin_inff(); l_run[rf][r] = 0.f; }

    const int kr = tid >> 4;              // 0..31
    const int kc = (tid & 15) * 8;        // 0..120
    const int vd = wave * 16;

    {   // stage tile 0 synchronously
#pragma unroll
        for (int p = 0; p < 2; ++p)
            *(int4_*)&Ks[kr + p * 32][kc] =
                *(const int4_*)&Kp[(size_t)(kr + p * 32) * 128 + kc];
        union { int4_ v; bf16 h[8]; } u;
#pragma unroll
        for (int p = 0; p < 2; ++p) {
            u.v = *(const int4_*)&Vp[(size_t)ln * 128 + vd + p * 8];
#pragma unroll
            for (int j = 0; j < 8; ++j)
                Vt[vd + p * 8 + j][ln] = u.h[j];
        }
    }
    __syncthreads();

    for (int kt = 0; kt <= ktmax; ++kt) {
        const bool more = (kt < ktmax);

        int4_ kpre0, kpre1, vpre0, vpre1;  // T14 issue-early
        if (more) {
            const int krow = (kt + 1) * 64;
            kpre0 = *(const int4_*)&Kp[(size_t)(krow + kr) * 128 + kc];
            kpre1 = *(const int4_*)&Kp[(size_t)(krow + kr + 32) * 128 + kc];
            vpre0 = *(const int4_*)&Vp[(size_t)(krow + ln) * 128 + vd];
            vpre1 = *(const int4_*)&Vp[(size_t)(krow + ln) * 128 + vd + 8];
        }

        if (kt <= dt) {                   // wave-uniform causal skip
            // ---- QK^T: shared kf read feeds both row-frags ----
            float4_ sacc[2][4];
            __builtin_amdgcn_s_setprio(1);
#pragma unroll
            for (int nf = 0; nf < 4; ++nf) {
                sacc[0][nf] = fzero;
                sacc[1][nf] = fzero;
#pragma unroll
                for (int ks = 0; ks < 4; ++ks) {
                    short8 kf = *(const short8*)&Ks[nf * 16 + r15][ks * 32 + quad * 8];
                    sacc[0][nf] = MFMA_BF16(qf[0][ks], kf, sacc[0][nf]);
                    sacc[1][nf] = MFMA_BF16(qf[1][ks], kf, sacc[1][nf]);
                }
            }
            __builtin_amdgcn_s_setprio(0);

            if (kt == dt) {               // diagonal tile: element mask
#pragma unroll
                for (int rf = 0; rf < 2; ++rf) {
                    const int ro = (qrow0 & 63) + rf * 16 + quad * 4;
#pragma unroll
                    for (int nf = 0; nf < 4; ++nf) {
                        const int col = nf * 16 + r15;
#pragma unroll
                        for (int r = 0; r < 4; ++r)
                            if (col > ro + r) sacc[rf][nf][r] = -__builtin_inff();
                    }
                }
            }

            // ---- online softmax per row-frag ----
#pragma unroll
            for (int rf = 0; rf < 2; ++rf) {
                float mnew[4], alpha[4];
#pragma unroll
                for (int r = 0; r < 4; ++r) {
                    float rm = fmaxf(fmaxf(sacc[rf][0][r], sacc[rf][1][r]),
                                     fmaxf(sacc[rf][2][r], sacc[rf][3][r]));
                    rm = fmaxf(rm, __shfl_xor(rm, 1));
                    rm = fmaxf(rm, __shfl_xor(rm, 2));
                    rm = fmaxf(rm, __shfl_xor(rm, 4));
                    rm = fmaxf(rm, __shfl_xor(rm, 8));
                    mnew[r]  = fmaxf(m_run[rf][r], rm);
                    alpha[r] = __expf(m_run[rf][r] - mnew[r]);
                    m_run[rf][r] = mnew[r];
                }
                float rs[4] = {0.f, 0.f, 0.f, 0.f};
#pragma unroll
                for (int nf = 0; nf < 4; ++nf) {
#pragma unroll
                    for (int r = 0; r < 4; ++r) {
                        const float pp = __expf(sacc[rf][nf][r] - mnew[r]);
                        rs[r] += pp;
                        Ps[wave][rf * 16 + quad * 4 + r][nf * 16 + r15] = f2bf(pp);
                    }
                }
#pragma unroll
                for (int r = 0; r < 4; ++r) {
                    float t = rs[r];
                    t += __shfl_xor(t, 1);
                    t += __shfl_xor(t, 2);
                    t += __shfl_xor(t, 4);
                    t += __shfl_xor(t, 8);
                    l_run[rf][r] = l_run[rf][r] * alpha[r] + t;
                }
#pragma unroll
                for (int of = 0; of < 8; ++of)
#pragma unroll
                    for (int r = 0; r < 4; ++r)
                        acc_o[rf][of][r] *= alpha[r];
            }

            // ---- PV: shared vf read feeds both row-frags ----
            __builtin_amdgcn_s_setprio(1);
#pragma unroll
            for (int k2 = 0; k2 < 2; ++k2) {
                short8 pf0 = *(const short8*)&Ps[wave][r15][k2 * 32 + quad * 8];
                short8 pf1 = *(const short8*)&Ps[wave][16 + r15][k2 * 32 + quad * 8];
#pragma unroll
                for (int of = 0; of < 8; ++of) {
                    short8 vf = *(const short8*)&Vt[of * 16 + r15][k2 * 32 + quad * 8];
                    acc_o[0][of] = MFMA_BF16(pf0, vf, acc_o[0][of]);
                    acc_o[1][of] = MFMA_BF16(pf1, vf, acc_o[1][of]);
                }
            }
            __builtin_amdgcn_s_setprio(0);
        }

        __syncthreads();                  // all waves done reading Ks/Vt
        if (more) {                       // T14 write-late
            *(int4_*)&Ks[kr][kc]      = kpre0;
            *(int4_*)&Ks[kr + 32][kc] = kpre1;
            union { int4_ v; bf16 h[8]; } u;
            u.v = vpre0;
#pragma unroll
            for (int j = 0; j < 8; ++j) Vt[vd + j][ln] = u.h[j];
            u.v = vpre1;
#pragma unroll
            for (int j = 0; j < 8; ++j) Vt[vd + 8 + j][ln] = u.h[j];
        }
        __syncthreads();
    }

    // epilogue: O[b][s][h][d], both row-frags
#pragma unroll
    for (int rf = 0; rf < 2; ++rf) {
#pragma unroll
        for (int r = 0; r < 4; ++r) {
            const float inv = 1.f / l_run[rf][r];
            const int  s  = qrow0 + rf * 16 + quad * 4 + r;
            const size_t ob = (((size_t)b * S + s) * 16 + h) * 128;
#pragma unroll
            for (int of = 0; of < 8; ++of)
                Og[ob + of * 16 + r15] = f2bf(acc_o[rf][of][r] * inv);
        }
    }
}

// ---------------------------------------------------------------------------
extern "C" void kernel_launch(void* const* d_in, const int* in_sizes, int n_in,
                              void* d_out, int out_size, void* d_ws, size_t ws_size,
                              hipStream_t stream)
{
    const float* X  = (const float*)d_in[0];
    const float* Wq = (const float*)d_in[1];
    const float* Wk = (const float*)d_in[2];
    const float* Wv = (const float*)d_in[3];
    const float* Wo = (const float*)d_in[4];
    float* out = (float*)d_out;

    bf16* Xb  = (bf16*)d_ws;                 // 8388608
    bf16* Wqb = Xb  + 8388608;               // contiguous [6144][2048]: Wq,Wk,Wv
    bf16* Wkb = Wqb + 4194304;
    bf16* Wvb = Wkb + 4194304;
    bf16* Wob = Wvb + 4194304;
    bf16* q   = Wob + 4194304;               // contiguous [3][B][NH][S][HD]
    bf16* k   = q   + 8388608;
    bf16* v   = k   + 8388608;
    bf16* ao  = v   + 8388608;               // [B][S][NH][HD]

    dim3 blk(256);
    cvt_all<<<dim3(12288), blk, 0, stream>>>(X, Wq, Wk, Wv, Wo,
                                             Xb, Wqb, Wkb, Wvb, Wob);
    // merged QKV: C[4096][6144] = Xb * [Wq;Wk;Wv]^T, 768 blocks = 3 rounds
    gemm_bn128<<<dim3(48, 16), dim3(512), 0, stream>>>(Xb, Wqb, q, nullptr, 0);
    rope_scale<<<dim3((2 * 16 * 2048 * 64) / 256), blk, 0, stream>>>(q, k);
    // pair-balanced causal flash, wave-per-strip: 256 blocks, 34 units each
    flash_attn<<<dim3(8, 32), dim3(512), 0, stream>>>(q, k, v, ao);
    // O-proj: C[4096][2048] = ao * Wo^T, 256 blocks = 1 full round
    gemm_bn128<<<dim3(16, 16), dim3(512), 0, stream>>>(ao, Wob, nullptr, out, 1);
}

// Round 7
// 421.746 us; speedup vs baseline: 1.0434x; 1.0434x over previous
//
#include <hip/hip_runtime.h>
#include <hip/hip_bf16.h>

using bf16 = __hip_bfloat16;
typedef short  short8  __attribute__((ext_vector_type(8)));
typedef float  float4_ __attribute__((ext_vector_type(4)));
typedef int    int4_   __attribute__((ext_vector_type(4)));

typedef __attribute__((address_space(1))) const void* gas_ptr;
typedef __attribute__((address_space(3))) void*       las_ptr;

#define MFMA_BF16(a, b, c) __builtin_amdgcn_mfma_f32_16x16x32_bf16((a), (b), (c), 0, 0, 0)

__device__ __forceinline__ float bf2f(bf16 v) { return __bfloat162float(v); }
__device__ __forceinline__ bf16  f2bf(float v) { return __float2bfloat16(v); }

#define BAR() do { asm volatile("" ::: "memory"); __builtin_amdgcn_s_barrier(); asm volatile("" ::: "memory"); } while (0)
#define WAITLGKM0() asm volatile("s_waitcnt lgkmcnt(0)" ::: "memory")

// ---------------------------------------------------------------------------
// DPP 16-lane reductions (replace ds_bpermute shuffles with VALU):
// groups are lanes [quad*16 .. quad*16+15] = hardware DPP rows of 16.
// Coverage: xor1 (quad_perm 0xB1), xor2 (quad_perm 0x4E) -> per-quad reduce;
// row_ror:4 (0x124) -> {q, q+1}; row_ror:8 (0x128) -> all 4 quads, all lanes.
// ---------------------------------------------------------------------------
template<int CTRL>
__device__ __forceinline__ float dppmv(float x) {
    return __int_as_float(__builtin_amdgcn_update_dpp(
        0, __float_as_int(x), CTRL, 0xF, 0xF, true));
}
__device__ __forceinline__ float row16_max(float x) {
    x = fmaxf(x, dppmv<0xB1>(x));
    x = fmaxf(x, dppmv<0x4E>(x));
    x = fmaxf(x, dppmv<0x124>(x));
    x = fmaxf(x, dppmv<0x128>(x));
    return x;
}
__device__ __forceinline__ float row16_sum(float x) {
    x += dppmv<0xB1>(x);
    x += dppmv<0x4E>(x);
    x += dppmv<0x124>(x);
    x += dppmv<0x128>(x);
    return x;
}

// ---------------------------------------------------------------------------
// fp32 -> bf16 conversion of X + 4 weights into workspace (verified r2 form).
// ---------------------------------------------------------------------------
__global__ __launch_bounds__(256)
void cvt_all(const float* __restrict__ X,  const float* __restrict__ Wq,
             const float* __restrict__ Wk, const float* __restrict__ Wv,
             const float* __restrict__ Wo,
             bf16* __restrict__ Xb,  bf16* __restrict__ Wqb,
             bf16* __restrict__ Wkb, bf16* __restrict__ Wvb,
             bf16* __restrict__ Wob)
{
    const size_t i = ((size_t)blockIdx.x * 256 + threadIdx.x) * 8;
    const float* src; bf16* dst; size_t off;
    if (i < 8388608)       { src = X;  dst = Xb;  off = i; }
    else if (i < 12582912) { src = Wq; dst = Wqb; off = i - 8388608; }
    else if (i < 16777216) { src = Wk; dst = Wkb; off = i - 12582912; }
    else if (i < 20971520) { src = Wv; dst = Wvb; off = i - 16777216; }
    else                   { src = Wo; dst = Wob; off = i - 20971520; }
    const float4_ a = *(const float4_*)(src + off);
    const float4_ b = *(const float4_*)(src + off + 4);
    union { short8 s; bf16 h[8]; } u;
#pragma unroll
    for (int j = 0; j < 4; ++j) { u.h[j] = f2bf(a[j]); u.h[j + 4] = f2bf(b[j]); }
    *(short8*)(dst + off) = u.s;
}

// ---------------------------------------------------------------------------
// 256x128 2-phase-per-tile MFMA GEMM (verified r4/r5: QKV 768 blocks = 3
// rounds, O-proj 256 = 1 round; T2 swizzle, counted vmcnt(5), tail drain,
// setprio). FROZEN.
// mode 0: scatter bf16 to Oq = q/k/v [3][B][NH][S][HD], N=6144 merged QKV.
// mode 1: row-major fp32 OF, N=2048.
// ---------------------------------------------------------------------------
__global__ __launch_bounds__(512, 2)
void gemm_bn128(const bf16* __restrict__ Ap, const bf16* __restrict__ Wp,
                bf16* __restrict__ Oq, float* __restrict__ OF, int mode)
{
    constexpr int NT = 32;                       // K=2048 / BK=64
    __shared__ bf16 As0[2 * 256 * 64];           // 64 KiB [buf][row][64]
    __shared__ bf16 Bs0[2 * 128 * 64];           // 32 KiB

    const int nwg  = gridDim.x * gridDim.y;
    const int bid0 = blockIdx.y * gridDim.x + blockIdx.x;
    const int cpx  = nwg >> 3;
    const int swzb = (bid0 & 7) * cpx + (bid0 >> 3);
    const int bn = (swzb % gridDim.x) * 128;
    const int bm = (swzb / gridDim.x) * 256;

    const int tid  = threadIdx.x;
    const int w    = tid >> 6;                   // 0..7
    const int ln   = tid & 63;
    const int r15  = ln & 15;
    const int quad = ln >> 4;
    const int wr   = w >> 1;                     // 0..3 (M)
    const int wc   = w & 1;                      // 0..1 (N)

    const int srow = ln >> 3;                                // 0..7
    const int scol = ((ln & 7) ^ srow) * 8;                  // elements
    const int w8   = w * 8;
    const int cx   = (r15 & 7) * 8;                          // read-side XOR

#define STAGE_A(pb, ts) do {                                                \
    _Pragma("unroll")                                                       \
    for (int c = 0; c < 4; ++c) {                                           \
        const int rl = c * 64 + w8;                                         \
        __builtin_amdgcn_global_load_lds(                                   \
            (gas_ptr)(Ap + (size_t)(bm + rl + srow) * 2048 + (ts) * 64 + scol), \
            (las_ptr)(As0 + (pb) * 16384 + rl * 64), 16, 0, 0);             \
    } } while (0)

#define STAGE_B0(pb, ts) do {                                               \
    const int rl = w8;                                                      \
    __builtin_amdgcn_global_load_lds(                                       \
        (gas_ptr)(Wp + (size_t)(bn + rl + srow) * 2048 + (ts) * 64 + scol), \
        (las_ptr)(Bs0 + (pb) * 8192 + rl * 64), 16, 0, 0);                  \
    } while (0)

#define STAGE_B1(pb, ts) do {                                               \
    const int rl = 64 + w8;                                                 \
    __builtin_amdgcn_global_load_lds(                                       \
        (gas_ptr)(Wp + (size_t)(bn + rl + srow) * 2048 + (ts) * 64 + scol), \
        (las_ptr)(Bs0 + (pb) * 8192 + rl * 64), 16, 0, 0);                  \
    } while (0)

#define LDA() do {                                                          \
    _Pragma("unroll")                                                       \
    for (int mi = 0; mi < 4; ++mi) {                                        \
        const int row = wr * 64 + mi * 16 + r15;                            \
        a[mi][0] = *(const short8*)(As0 + p * 16384 + row * 64 + ((quad * 8) ^ cx));      \
        a[mi][1] = *(const short8*)(As0 + p * 16384 + row * 64 + ((32 + quad * 8) ^ cx)); \
    } } while (0)

#define LDB(qn) do {                                                        \
    _Pragma("unroll")                                                       \
    for (int j = 0; j < 2; ++j) {                                           \
        const int row = wc * 64 + ((qn) * 2 + j) * 16 + r15;                \
        b[j][0] = *(const short8*)(Bs0 + p * 8192 + row * 64 + ((quad * 8) ^ cx));      \
        b[j][1] = *(const short8*)(Bs0 + p * 8192 + row * 64 + ((32 + quad * 8) ^ cx)); \
    } } while (0)

#define MM(qn) do {                                                         \
    __builtin_amdgcn_s_setprio(1);                                          \
    _Pragma("unroll")                                                       \
    for (int mi = 0; mi < 4; ++mi)                                          \
        _Pragma("unroll")                                                   \
        for (int j = 0; j < 2; ++j)                                         \
            _Pragma("unroll")                                               \
            for (int kk = 0; kk < 2; ++kk)                                  \
                acc[mi][(qn) * 2 + j] =                                     \
                    MFMA_BF16(a[mi][kk], b[j][kk], acc[mi][(qn) * 2 + j]);  \
    __builtin_amdgcn_s_setprio(0); } while (0)

    float4_ acc[4][4];
    const float4_ fzero = {0.f, 0.f, 0.f, 0.f};
#pragma unroll
    for (int i = 0; i < 4; ++i)
#pragma unroll
        for (int j = 0; j < 4; ++j) acc[i][j] = fzero;

    short8 a[4][2], b[2][2];

    STAGE_A(0, 0); STAGE_B0(0, 0); STAGE_B1(0, 0);
    STAGE_A(1, 1); STAGE_B0(1, 1);
    asm volatile("s_waitcnt vmcnt(5)" ::: "memory");
    BAR();

    for (int t = 0; t < NT; ++t) {
        const int p = t & 1, pq = p ^ 1;
        LDA(); LDB(0);
        if (t + 1 < NT) STAGE_B1(pq, t + 1);
        asm volatile("s_waitcnt lgkmcnt(8)" ::: "memory");
        BAR(); WAITLGKM0();
        MM(0);
        BAR();
        LDB(1);
        if (t + 2 < NT) { STAGE_A(p, t + 2); STAGE_B0(p, t + 2); }
        BAR(); WAITLGKM0();
        MM(1);
        if (t >= NT - 2) { asm volatile("s_waitcnt vmcnt(0)" ::: "memory"); }
        else             { asm volatile("s_waitcnt vmcnt(5)" ::: "memory"); }
        BAR();
    }

#pragma unroll
    for (int mi = 0; mi < 4; ++mi) {
#pragma unroll
        for (int ni = 0; ni < 4; ++ni) {
#pragma unroll
            for (int r = 0; r < 4; ++r) {
                const int row = bm + wr * 64 + mi * 16 + quad * 4 + r;
                const int col = bn + wc * 64 + ni * 16 + r15;
                const float v = acc[mi][ni][r];
                if (mode == 0) {
                    const int z = col >> 11, c2 = col & 2047;
                    const int h = c2 >> 7, d = c2 & 127;
                    const int bb = row >> 11, s = row & 2047;
                    Oq[(size_t)z * 8388608 + (((size_t)bb * 16 + h) * 2048 + s) * 128 + d] = f2bf(v);
                } else {
                    OF[(size_t)row * 2048 + col] = v;
                }
            }
        }
    }
#undef STAGE_A
#undef STAGE_B0
#undef STAGE_B1
#undef LDA
#undef LDB
#undef MM
}

// ---------------------------------------------------------------------------
// RoPE on Q and K ([B][NH][S][HD] bf16); folds 1/sqrt(128) into Q.
// ---------------------------------------------------------------------------
__global__ __launch_bounds__(256)
void rope_scale(bf16* __restrict__ Q, bf16* __restrict__ Kb)
{
    const int idx = blockIdx.x * 256 + threadIdx.x;
    const int d  = idx & 63;
    const int s  = (idx >> 6) & 2047;
    const int bh = idx >> 17;
    const size_t base = ((size_t)bh * 2048 + s) * 128;

    const float inv_freq = expf(-(float)d * (9.210340371976184f / 64.f));
    const float ang = (float)s * inv_freq;
    const float c = cosf(ang), sn = sinf(ang);
    const float sc = 0.08838834764831845f;

    const float q1 = bf2f(Q[base + d]), q2 = bf2f(Q[base + d + 64]);
    Q[base + d]      = f2bf((q1 * c - q2 * sn) * sc);
    Q[base + d + 64] = f2bf((q2 * c + q1 * sn) * sc);

    const float k1 = bf2f(Kb[base + d]), k2 = bf2f(Kb[base + d + 64]);
    Kb[base + d]      = f2bf(k1 * c - k2 * sn);
    Kb[base + d + 64] = f2bf(k2 * c + k1 * sn);
}

// ---------------------------------------------------------------------------
// Causal MFMA flash attention, v5 (pair-balanced + wave-per-strip + DPP
// softmax reductions + T13 defer-max):
//  - structure verbatim from r6 (verified): 256 blocks, waves 0-3 lo strip /
//    4-7 hi strip, 32 Q-rows per wave, shared kf/vf reads, T14 async-STAGE.
//  - NEW 1: 16-lane max/sum reductions via DPP (row16_max/row16_sum) instead
//    of __shfl_xor chains -> removes 64 ds_bpermute/step from the LDS pipe
//    (~30% of flash's LDS bytes), which is the serializing resource.
//  - NEW 2: T13 defer-max THR=8 — skip the O-rescale (64 muls + 8 exps) when
//    the tile max didn't grow by >8 (wave-uniform __all); exact-math aside
//    from bf16 rounding, P bounded by e^8.
// Q,K,V: [B][NH][S][HD] bf16 (Q pre-scaled); O: [B][S][NH][HD] bf16.
// ---------------------------------------------------------------------------
__global__ __launch_bounds__(512)
void flash_attn(const bf16* __restrict__ Qg, const bf16* __restrict__ Kg,
                const bf16* __restrict__ Vg, bf16* __restrict__ Og)
{
    constexpr int S = 2048;
    const int pr = blockIdx.x;            // 0..7: strip pair (pr, 15-pr)
    const int bh = blockIdx.y;
    const int b = bh >> 4, h = bh & 15;
    const size_t base = (size_t)bh * S * 128;
    const bf16* Qp = Qg + base;
    const bf16* Kp = Kg + base;
    const bf16* Vp = Vg + base;

    const int tid  = threadIdx.x;
    const int wave = tid >> 6;            // 0..7
    const int ln   = tid & 63;
    const int r15  = ln & 15;
    const int quad = ln >> 4;
    const int sid  = wave & 3;            // sub-strip index within strip
    const int hi   = wave >> 2;           // 0 = lo strip, 1 = hi strip

    __shared__ bf16 Ks[64][136];          // K tile, 17.0 KB
    __shared__ bf16 Vt[128][72];          // V tile transposed, 18.0 KB
    __shared__ bf16 Ps[8][32][72];        // per-wave P (2 row-frags), 36.9 KB

    const int strip = hi ? (15 - pr) : pr;
    const int qrow0 = strip * 128 + sid * 32;   // this wave's 32 rows
    const int dt    = qrow0 >> 6;               // diagonal K-tile
    const int ktmax = 2 * (15 - pr) + 1;        // staging range (hi strip)

    short8 qf[2][4];
#pragma unroll
    for (int rf = 0; rf < 2; ++rf)
#pragma unroll
        for (int ks = 0; ks < 4; ++ks)
            qf[rf][ks] = *(const short8*)&Qp[(size_t)(qrow0 + rf * 16 + r15) * 128
                                             + ks * 32 + quad * 8];

    float4_ acc_o[2][8];
    const float4_ fzero = {0.f, 0.f, 0.f, 0.f};
#pragma unroll
    for (int rf = 0; rf < 2; ++rf)
#pragma unroll
        for (int of = 0; of < 8; ++of) acc_o[rf][of] = fzero;
    float m_run[2][4], l_run[2][4];
#pragma unroll
    for (int rf = 0; rf < 2; ++rf)
#pragma unroll
        for (int r = 0; r < 4; ++r) { m_run[rf][r] = -__builtin_inff(); l_run[rf][r] = 0.f; }

    const int kr = tid >> 4;              // 0..31
    const int kc = (tid & 15) * 8;        // 0..120
    const int vd = wave * 16;

    {   // stage tile 0 synchronously
#pragma unroll
        for (int p = 0; p < 2; ++p)
            *(int4_*)&Ks[kr + p * 32][kc] =
                *(const int4_*)&Kp[(size_t)(kr + p * 32) * 128 + kc];
        union { int4_ v; bf16 h[8]; } u;
#pragma unroll
        for (int p = 0; p < 2; ++p) {
            u.v = *(const int4_*)&Vp[(size_t)ln * 128 + vd + p * 8];
#pragma unroll
            for (int j = 0; j < 8; ++j)
                Vt[vd + p * 8 + j][ln] = u.h[j];
        }
    }
    __syncthreads();

    for (int kt = 0; kt <= ktmax; ++kt) {
        const bool more = (kt < ktmax);

        int4_ kpre0, kpre1, vpre0, vpre1;  // T14 issue-early
        if (more) {
            const int krow = (kt + 1) * 64;
            kpre0 = *(const int4_*)&Kp[(size_t)(krow + kr) * 128 + kc];
            kpre1 = *(const int4_*)&Kp[(size_t)(krow + kr + 32) * 128 + kc];
            vpre0 = *(const int4_*)&Vp[(size_t)(krow + ln) * 128 + vd];
            vpre1 = *(const int4_*)&Vp[(size_t)(krow + ln) * 128 + vd + 8];
        }

        if (kt <= dt) {                   // wave-uniform causal skip
            // ---- QK^T: shared kf read feeds both row-frags ----
            float4_ sacc[2][4];
            __builtin_amdgcn_s_setprio(1);
#pragma unroll
            for (int nf = 0; nf < 4; ++nf) {
                sacc[0][nf] = fzero;
                sacc[1][nf] = fzero;
#pragma unroll
                for (int ks = 0; ks < 4; ++ks) {
                    short8 kf = *(const short8*)&Ks[nf * 16 + r15][ks * 32 + quad * 8];
                    sacc[0][nf] = MFMA_BF16(qf[0][ks], kf, sacc[0][nf]);
                    sacc[1][nf] = MFMA_BF16(qf[1][ks], kf, sacc[1][nf]);
                }
            }
            __builtin_amdgcn_s_setprio(0);

            if (kt == dt) {               // diagonal tile: element mask
#pragma unroll
                for (int rf = 0; rf < 2; ++rf) {
                    const int ro = (qrow0 & 63) + rf * 16 + quad * 4;
#pragma unroll
                    for (int nf = 0; nf < 4; ++nf) {
                        const int col = nf * 16 + r15;
#pragma unroll
                        for (int r = 0; r < 4; ++r)
                            if (col > ro + r) sacc[rf][nf][r] = -__builtin_inff();
                    }
                }
            }

            // ---- online softmax per row-frag (DPP reduce + defer-max) ----
#pragma unroll
            for (int rf = 0; rf < 2; ++rf) {
                float rm4[4];
                float g = 0.f;
#pragma unroll
                for (int r = 0; r < 4; ++r) {
                    float rm = fmaxf(fmaxf(sacc[rf][0][r], sacc[rf][1][r]),
                                     fmaxf(sacc[rf][2][r], sacc[rf][3][r]));
                    rm4[r] = row16_max(rm);
                    g = fmaxf(g, rm4[r] - m_run[rf][r]);
                }
                const bool resc = !__all(g <= 8.f);   // T13: rescale only on growth
                float mnew[4], alpha[4];
                if (resc) {
#pragma unroll
                    for (int r = 0; r < 4; ++r) {
                        mnew[r]  = fmaxf(m_run[rf][r], rm4[r]);
                        alpha[r] = __expf(m_run[rf][r] - mnew[r]);
                        m_run[rf][r] = mnew[r];
                    }
                } else {
#pragma unroll
                    for (int r = 0; r < 4; ++r) { mnew[r] = m_run[rf][r]; alpha[r] = 1.f; }
                }
                float rs[4] = {0.f, 0.f, 0.f, 0.f};
#pragma unroll
                for (int nf = 0; nf < 4; ++nf) {
#pragma unroll
                    for (int r = 0; r < 4; ++r) {
                        const float pp = __expf(sacc[rf][nf][r] - mnew[r]);
                        rs[r] += pp;
                        Ps[wave][rf * 16 + quad * 4 + r][nf * 16 + r15] = f2bf(pp);
                    }
                }
#pragma unroll
                for (int r = 0; r < 4; ++r) {
                    const float t = row16_sum(rs[r]);
                    l_run[rf][r] = resc ? (l_run[rf][r] * alpha[r] + t)
                                        : (l_run[rf][r] + t);
                }
                if (resc) {
#pragma unroll
                    for (int of = 0; of < 8; ++of)
#pragma unroll
                        for (int r = 0; r < 4; ++r)
                            acc_o[rf][of][r] *= alpha[r];
                }
            }

            // ---- PV: shared vf read feeds both row-frags ----
            __builtin_amdgcn_s_setprio(1);
#pragma unroll
            for (int k2 = 0; k2 < 2; ++k2) {
                short8 pf0 = *(const short8*)&Ps[wave][r15][k2 * 32 + quad * 8];
                short8 pf1 = *(const short8*)&Ps[wave][16 + r15][k2 * 32 + quad * 8];
#pragma unroll
                for (int of = 0; of < 8; ++of) {
                    short8 vf = *(const short8*)&Vt[of * 16 + r15][k2 * 32 + quad * 8];
                    acc_o[0][of] = MFMA_BF16(pf0, vf, acc_o[0][of]);
                    acc_o[1][of] = MFMA_BF16(pf1, vf, acc_o[1][of]);
                }
            }
            __builtin_amdgcn_s_setprio(0);
        }

        __syncthreads();                  // all waves done reading Ks/Vt
        if (more) {                       // T14 write-late
            *(int4_*)&Ks[kr][kc]      = kpre0;
            *(int4_*)&Ks[kr + 32][kc] = kpre1;
            union { int4_ v; bf16 h[8]; } u;
            u.v = vpre0;
#pragma unroll
            for (int j = 0; j < 8; ++j) Vt[vd + j][ln] = u.h[j];
            u.v = vpre1;
#pragma unroll
            for (int j = 0; j < 8; ++j) Vt[vd + 8 + j][ln] = u.h[j];
        }
        __syncthreads();
    }

    // epilogue: O[b][s][h][d], both row-frags
#pragma unroll
    for (int rf = 0; rf < 2; ++rf) {
#pragma unroll
        for (int r = 0; r < 4; ++r) {
            const float inv = 1.f / l_run[rf][r];
            const int  s  = qrow0 + rf * 16 + quad * 4 + r;
            const size_t ob = (((size_t)b * S + s) * 16 + h) * 128;
#pragma unroll
            for (int of = 0; of < 8; ++of)
                Og[ob + of * 16 + r15] = f2bf(acc_o[rf][of][r] * inv);
        }
    }
}

// ---------------------------------------------------------------------------
extern "C" void kernel_launch(void* const* d_in, const int* in_sizes, int n_in,
                              void* d_out, int out_size, void* d_ws, size_t ws_size,
                              hipStream_t stream)
{
    const float* X  = (const float*)d_in[0];
    const float* Wq = (const float*)d_in[1];
    const float* Wk = (const float*)d_in[2];
    const float* Wv = (const float*)d_in[3];
    const float* Wo = (const float*)d_in[4];
    float* out = (float*)d_out;

    bf16* Xb  = (bf16*)d_ws;                 // 8388608
    bf16* Wqb = Xb  + 8388608;               // contiguous [6144][2048]: Wq,Wk,Wv
    bf16* Wkb = Wqb + 4194304;
    bf16* Wvb = Wkb + 4194304;
    bf16* Wob = Wvb + 4194304;
    bf16* q   = Wob + 4194304;               // contiguous [3][B][NH][S][HD]
    bf16* k   = q   + 8388608;
    bf16* v   = k   + 8388608;
    bf16* ao  = v   + 8388608;               // [B][S][NH][HD]

    dim3 blk(256);
    cvt_all<<<dim3(12288), blk, 0, stream>>>(X, Wq, Wk, Wv, Wo,
                                             Xb, Wqb, Wkb, Wvb, Wob);
    // merged QKV: C[4096][6144] = Xb * [Wq;Wk;Wv]^T, 768 blocks = 3 rounds
    gemm_bn128<<<dim3(48, 16), dim3(512), 0, stream>>>(Xb, Wqb, q, nullptr, 0);
    rope_scale<<<dim3((2 * 16 * 2048 * 64) / 256), blk, 0, stream>>>(q, k);
    // pair-balanced causal flash, wave-per-strip: 256 blocks, 34 units each
    flash_attn<<<dim3(8, 32), dim3(512), 0, stream>>>(q, k, v, ao);
    // O-proj: C[4096][2048] = ao * Wo^T, 256 blocks = 1 full round
    gemm_bn128<<<dim3(16, 16), dim3(512), 0, stream>>>(ao, Wob, nullptr, out, 1);
}